// Round 3
// baseline (544.133 us; speedup 1.0000x reference)
//
#include <hip/hip_runtime.h>
#include <hip/hip_bf16.h>

typedef __attribute__((ext_vector_type(8))) short short8;
typedef __attribute__((ext_vector_type(4))) float f32x4;

#define NN 16384
#define DD 128
#define NE 262144
#define NG 32
#define SS 512
#define NH 8
#define DHD 16
#define EPG 8192   // edges per graph
#define NSPLIT 4   // edge-chunks per (graph,q) block -> 4 agg part buffers
#define BN_EPS 1e-5f

__device__ __forceinline__ unsigned int pk2(float a, float b) {
    union { __hip_bfloat16 h; unsigned short u; } ca, cb;
    ca.h = __float2bfloat16(a);
    cb.h = __float2bfloat16(b);
    return (unsigned int)ca.u | ((unsigned int)cb.u << 16);
}

// -------- GINE scatter via per-(graph, q-chunk, edge-chunk) LDS slab ---------------
// id = c*256 + q*32 + g : all 32 blocks of graph g are == g (mod 8) -> one XCD,
// so edge_attr 128B lines split across q-pairs stay L2-local. 1024 blocks ->
// 4 blocks/CU (LDS-capped), 32 waves/CU. Each block owns one quarter of the
// graph's edges and writes a private agg part; GEMM1 sums the 4 parts (no atomics).
__global__ __launch_bounds__(512) void gine_scatter_lds(
    const float* __restrict__ x, const int* __restrict__ src, const int* __restrict__ dst,
    const float* __restrict__ ea, float* __restrict__ agg_parts)
{
    __shared__ float slab[512 * 17];   // stride 17: spreads LDS-atomic banks
    const int g = blockIdx.x & 31;
    const int q = (blockIdx.x >> 5) & 7;
    const int c = blockIdx.x >> 8;
    const int t = threadIdx.x;
    for (int i = t; i < 512 * 17; i += 512) slab[i] = 0.f;
    __syncthreads();

    const int ebase = g * EPG + c * (EPG / NSPLIT);
    const int lane4 = t & 3;
    const int esub  = t >> 2;           // 128 edges per iteration
    #pragma unroll 4
    for (int it = 0; it < EPG / NSPLIT / 128; ++it) {
        int e = ebase + it * 128 + esub;
        int s = src[e];
        int d = dst[e] - g * SS;
        float4 xv = *(const float4*)(x  + (size_t)s * DD + q * 16 + lane4 * 4);
        float4 ev = *(const float4*)(ea + (size_t)e * DD + q * 16 + lane4 * 4);
        float m0 = fmaxf(xv.x + ev.x, 0.f);
        float m1 = fmaxf(xv.y + ev.y, 0.f);
        float m2 = fmaxf(xv.z + ev.z, 0.f);
        float m3 = fmaxf(xv.w + ev.w, 0.f);
        float* p = slab + d * 17 + lane4 * 4;
        atomicAdd(p + 0, m0);
        atomicAdd(p + 1, m1);
        atomicAdd(p + 2, m2);
        atomicAdd(p + 3, m3);
    }
    __syncthreads();
    float* part = agg_parts + (size_t)c * NN * DD;
    for (int i = t; i < 512 * 4; i += 512) {
        int r = i >> 2;
        int col = (i & 3) * 4;
        float4 v = { slab[r * 17 + col], slab[r * 17 + col + 1],
                     slab[r * 17 + col + 2], slab[r * 17 + col + 3] };
        *(float4*)(part + ((size_t)(g * SS + r)) * DD + q * 16 + col) = v;
    }
}

// ---------------- bf16 MFMA GEMM, BT layout: out = epi(A(+parts) @ W^T + bias) -----
// A: [M,K] f32 row-major, W: [Ncols,K] f32 row-major. BM=BN=128, BK=64, 4 waves.
// N_A2 part buffers (stride NN*DD) are summed into A during staging (needs K==DD).
// STATS: fuse per-column sum/sumsq (BatchNorm) — requires Ncols==128, gridDim.y==1.
template<bool RELU, int N_A2, bool HAS_RES, bool STATS>
__global__ __launch_bounds__(256) void gemm_bt(
    const float* __restrict__ A, const float* __restrict__ A2,
    const float* __restrict__ W, const float* __restrict__ bias,
    const float* __restrict__ res, float* __restrict__ out,
    float* __restrict__ stats, int K, int Ncols)
{
    constexpr int BK = 64;
    __shared__ unsigned short Ash[128 * BK];
    __shared__ unsigned short Wsh[128 * BK];
    __shared__ float ssh[256];
    const int tid  = threadIdx.x;
    const int lane = tid & 63;
    const int wid  = tid >> 6;
    const int wm   = wid >> 1, wn = wid & 1;
    const int brow = blockIdx.x * 128;
    const int bcol = blockIdx.y * 128;

    f32x4 acc[4][4] = {};

    for (int k0 = 0; k0 < K; k0 += BK) {
        #pragma unroll
        for (int i = 0; i < 4; ++i) {
            int idx = tid + 256 * i;
            int row = idx >> 3;
            int kc  = (idx & 7) * 8;
            int off = row * (BK * 2) + ((kc * 2) ^ ((row & 7) << 4));
            {
                size_t base = (size_t)(brow + row) * K + k0 + kc;
                float4 lo = *(const float4*)(A + base);
                float4 hi = *(const float4*)(A + base + 4);
                #pragma unroll
                for (int p = 0; p < N_A2; ++p) {
                    const float* s2 = A2 + (size_t)p * NN * DD + base;
                    float4 l2 = *(const float4*)s2;
                    float4 h2 = *(const float4*)(s2 + 4);
                    lo.x += l2.x; lo.y += l2.y; lo.z += l2.z; lo.w += l2.w;
                    hi.x += h2.x; hi.y += h2.y; hi.z += h2.z; hi.w += h2.w;
                }
                int4 pw = { (int)pk2(lo.x, lo.y), (int)pk2(lo.z, lo.w),
                            (int)pk2(hi.x, hi.y), (int)pk2(hi.z, hi.w) };
                *(int4*)((char*)Ash + off) = pw;
            }
            {
                const float* sp = W + (size_t)(bcol + row) * K + k0 + kc;
                float4 lo = *(const float4*)sp;
                float4 hi = *(const float4*)(sp + 4);
                int4 pw = { (int)pk2(lo.x, lo.y), (int)pk2(lo.z, lo.w),
                            (int)pk2(hi.x, hi.y), (int)pk2(hi.z, hi.w) };
                *(int4*)((char*)Wsh + off) = pw;
            }
        }
        __syncthreads();
        #pragma unroll
        for (int ks = 0; ks < BK / 32; ++ks) {
            short8 af[4], bf[4];
            const int kf = ks * 32 + (lane >> 4) * 8;
            #pragma unroll
            for (int mt = 0; mt < 4; ++mt) {
                int row = wm * 64 + mt * 16 + (lane & 15);
                int off = row * (BK * 2) + ((kf * 2) ^ ((row & 7) << 4));
                af[mt] = *(const short8*)((const char*)Ash + off);
            }
            #pragma unroll
            for (int nt = 0; nt < 4; ++nt) {
                int row = wn * 64 + nt * 16 + (lane & 15);
                int off = row * (BK * 2) + ((kf * 2) ^ ((row & 7) << 4));
                bf[nt] = *(const short8*)((const char*)Wsh + off);
            }
            #pragma unroll
            for (int mt = 0; mt < 4; ++mt)
                #pragma unroll
                for (int nt = 0; nt < 4; ++nt)
                    acc[mt][nt] = __builtin_amdgcn_mfma_f32_16x16x32_bf16(
                        af[mt], bf[nt], acc[mt][nt], 0, 0, 0);
        }
        __syncthreads();
    }

    if (STATS) { ssh[tid] = 0.f; __syncthreads(); }

    float cs[4] = {}, cs2[4] = {};
    // epilogue: C/D layout col=lane&15, row=(lane>>4)*4+j (verified gfx950 mapping)
    #pragma unroll
    for (int mt = 0; mt < 4; ++mt) {
        #pragma unroll
        for (int nt = 0; nt < 4; ++nt) {
            int col = bcol + wn * 64 + nt * 16 + (lane & 15);
            float bv = bias[col];
            #pragma unroll
            for (int j = 0; j < 4; ++j) {
                int row = brow + wm * 64 + mt * 16 + (lane >> 4) * 4 + j;
                float v = acc[mt][nt][j] + bv;
                if (RELU) v = fmaxf(v, 0.f);
                if (HAS_RES) v += res[(size_t)row * Ncols + col];
                out[(size_t)row * Ncols + col] = v;
                if (STATS) { cs[nt] += v; cs2[nt] += v * v; }
            }
        }
    }
    if (STATS) {
        #pragma unroll
        for (int nt = 0; nt < 4; ++nt) {
            float s = cs[nt], s2 = cs2[nt];
            s  += __shfl_xor(s, 16);  s  += __shfl_xor(s, 32);
            s2 += __shfl_xor(s2, 16); s2 += __shfl_xor(s2, 32);
            if ((lane >> 4) == 0) {
                int cl = wn * 64 + nt * 16 + (lane & 15);
                atomicAdd(&ssh[cl], s);
                atomicAdd(&ssh[128 + cl], s2);
            }
        }
        __syncthreads();
        if (tid < 128) {
            atomicAdd(&stats[tid], ssh[tid]);
            atomicAdd(&stats[DD + tid], ssh[128 + tid]);
        }
    }
}

// ---------------- per-(graph,head) attention, f32, K/V staged in LDS ----------------
__global__ __launch_bounds__(512) void attn_kernel(
    const float* __restrict__ qkv, float* __restrict__ o)
{
    int g = blockIdx.x >> 3;
    int h = blockIdx.x & 7;
    __shared__ float Ksh[SS][DHD];
    __shared__ float Vsh[SS][DHD];
    int t = threadIdx.x;
    const float* rowp = qkv + (size_t)(g * SS + t) * 384;
    {
        const float* kb = rowp + 128 + h * DHD;
        const float* vb = rowp + 256 + h * DHD;
        #pragma unroll
        for (int i = 0; i < 4; ++i) {
            ((float4*)Ksh[t])[i] = ((const float4*)kb)[i];
            ((float4*)Vsh[t])[i] = ((const float4*)vb)[i];
        }
    }
    float q[DHD];
    {
        const float* qb = rowp + h * DHD;
        #pragma unroll
        for (int i = 0; i < 4; ++i) ((float4*)q)[i] = ((const float4*)qb)[i];
    }
    __syncthreads();
    float acc[DHD] = {};
    float l = 0.f;
    for (int j = 0; j < SS; ++j) {
        float s = 0.f;
        #pragma unroll
        for (int d = 0; d < DHD; ++d) s += q[d] * Ksh[j][d];
        float e = __expf(s * 0.25f);   // logits are O(1): max-subtraction unnecessary
        l += e;
        #pragma unroll
        for (int d = 0; d < DHD; ++d) acc[d] += e * Vsh[j][d];
    }
    float inv = 1.f / l;
    float* ob = o + (size_t)(g * SS + t) * DD + h * DHD;
    #pragma unroll
    for (int d = 0; d < DHD; ++d) acc[d] *= inv;
    #pragma unroll
    for (int i = 0; i < 4; ++i) ((float4*)ob)[i] = ((const float4*)acc)[i];
}

// ---------------- h = BN(t_local) + BN(t_attn) ----------------
__global__ __launch_bounds__(256) void combine_kernel(
    const float* __restrict__ tl, const float* __restrict__ ta,
    const float* __restrict__ stl, const float* __restrict__ sta,
    const float* __restrict__ g1, const float* __restrict__ b1,
    const float* __restrict__ g2, const float* __restrict__ b2,
    float* __restrict__ out)
{
    int idx = blockIdx.x * 256 + threadIdx.x;
    int c0 = (idx * 4) & (DD - 1);
    float4 vl = ((const float4*)tl)[idx];
    float4 va = ((const float4*)ta)[idx];
    float r[4];
    const float* pl = (const float*)&vl;
    const float* pa = (const float*)&va;
    #pragma unroll
    for (int k = 0; k < 4; ++k) {
        int c = c0 + k;
        float mu1 = stl[c] * (1.f / NN);
        float v1  = stl[DD + c] * (1.f / NN) - mu1 * mu1;
        float rs1 = rsqrtf(v1 + BN_EPS);
        float mu2 = sta[c] * (1.f / NN);
        float v2  = sta[DD + c] * (1.f / NN) - mu2 * mu2;
        float rs2 = rsqrtf(v2 + BN_EPS);
        r[k] = (pl[k] - mu1) * rs1 * g1[c] + b1[c]
             + (pa[k] - mu2) * rs2 * g2[c] + b2[c];
    }
    ((float4*)out)[idx] = *(float4*)r;
}

// ---------------- out = BN(t2) ----------------
__global__ __launch_bounds__(256) void final_bn(
    const float* __restrict__ t2, const float* __restrict__ st,
    const float* __restrict__ g, const float* __restrict__ b,
    float* __restrict__ out)
{
    int idx = blockIdx.x * 256 + threadIdx.x;
    int c0 = (idx * 4) & (DD - 1);
    float4 v = ((const float4*)t2)[idx];
    const float* pv = (const float*)&v;
    float r[4];
    #pragma unroll
    for (int k = 0; k < 4; ++k) {
        int c = c0 + k;
        float mu = st[c] * (1.f / NN);
        float va = st[DD + c] * (1.f / NN) - mu * mu;
        float rs = rsqrtf(va + BN_EPS);
        r[k] = (pv[k] - mu) * rs * g[c] + b[c];
    }
    ((float4*)out)[idx] = *(float4*)r;
}

extern "C" void kernel_launch(void* const* d_in, const int* in_sizes, int n_in,
                              void* d_out, int out_size, void* d_ws, size_t ws_size,
                              hipStream_t stream) {
    const float* x    = (const float*)d_in[0];
    const int*   ei   = (const int*)d_in[1];
    const float* ea   = (const float*)d_in[2];
    const float* gw1  = (const float*)d_in[3];
    const float* gb1  = (const float*)d_in[4];
    const float* gw2  = (const float*)d_in[5];
    const float* gb2  = (const float*)d_in[6];
    const float* bn1lg= (const float*)d_in[7];
    const float* bn1lb= (const float*)d_in[8];
    const float* aiw  = (const float*)d_in[9];
    const float* aib  = (const float*)d_in[10];
    const float* aow  = (const float*)d_in[11];
    const float* aob  = (const float*)d_in[12];
    const float* bn1ag= (const float*)d_in[13];
    const float* bn1ab= (const float*)d_in[14];
    const float* fw1  = (const float*)d_in[15];
    const float* fb1  = (const float*)d_in[16];
    const float* fw2  = (const float*)d_in[17];
    const float* fb2  = (const float*)d_in[18];
    const float* bn2g = (const float*)d_in[19];
    const float* bn2b = (const float*)d_in[20];
    float* out = (float*)d_out;
    float* ws  = (float*)d_ws;

    // ws regions (floats). 2,097,152 floats = one [NN,128] matrix.
    // A (8x): agg parts 0..3 (32MB) -> qkv (24MB) -> f1 (16MB)
    // B (2x): h1 -> o_buf ; C (2x): t_local -> t2 ; D: t_attn ; E: hbuf
    float* regA  = ws;                   // 8 * 2,097,152
    float* regB  = ws + 8 * 2097152;
    float* regC  = ws + 10 * 2097152;
    float* regD  = ws + 12 * 2097152;
    float* regE  = ws + 14 * 2097152;
    float* stats = ws + 16 * 2097152;    // 768 floats
    float* agg_parts = regA;
    float* qkv   = regA;
    float* f1    = regA;
    float* h1    = regB;
    float* o_buf = regB;
    float* t_local = regC;
    float* t2    = regC;
    float* t_attn = regD;
    float* hbuf  = regE;

    hipMemsetAsync(stats, 0, 768 * sizeof(float), stream);

    // --- local branch (parts fully overwritten by scatter; no memset, no atomics)
    gine_scatter_lds<<<NG * NH * NSPLIT, 512, 0, stream>>>(x, ei, ei + NE, ea, agg_parts);
    gemm_bt<true, NSPLIT, false, false><<<dim3(NN / 128, 1), 256, 0, stream>>>(
        x, agg_parts, gw1, gb1, nullptr, h1, nullptr, 128, 128);
    gemm_bt<false, 0, true, true><<<dim3(NN / 128, 1), 256, 0, stream>>>(
        h1, nullptr, gw2, gb2, x, t_local, stats, 128, 128);

    // --- global branch (qkv overlays agg parts, which die after gemm1)
    gemm_bt<false, 0, false, false><<<dim3(NN / 128, 3), 256, 0, stream>>>(
        x, nullptr, aiw, aib, nullptr, qkv, nullptr, 128, 384);
    attn_kernel<<<NG * NH, 512, 0, stream>>>(qkv, o_buf);
    gemm_bt<false, 0, true, true><<<dim3(NN / 128, 1), 256, 0, stream>>>(
        o_buf, nullptr, aow, aob, x, t_attn, stats + 256, 128, 128);

    // --- combine + FF
    combine_kernel<<<NN * DD / 4 / 256, 256, 0, stream>>>(
        t_local, t_attn, stats, stats + 256, bn1lg, bn1lb, bn1ag, bn1ab, hbuf);
    gemm_bt<true, 0, false, false><<<dim3(NN / 128, 2), 256, 0, stream>>>(
        hbuf, nullptr, fw1, fb1, nullptr, f1, nullptr, 128, 256);
    gemm_bt<false, 0, true, true><<<dim3(NN / 128, 1), 256, 0, stream>>>(
        f1, nullptr, fw2, fb2, hbuf, t2, stats + 512, 256, 128);
    final_bn<<<NN * DD / 4 / 256, 256, 0, stream>>>(t2, stats + 512, bn2g, bn2b, out);
}

// Round 4
// 445.840 us; speedup vs baseline: 1.2205x; 1.2205x over previous
//
#include <hip/hip_runtime.h>
#include <hip/hip_bf16.h>

typedef __attribute__((ext_vector_type(8))) short short8;
typedef __attribute__((ext_vector_type(4))) float f32x4;

#define NN 16384
#define DD 128
#define NE 262144
#define NG 32
#define SS 512
#define NH 8
#define DHD 16
#define EPG 8192   // edges per graph
#define BN_EPS 1e-5f

__device__ __forceinline__ unsigned int pk2(float a, float b) {
    union { __hip_bfloat16 h; unsigned short u; } ca, cb;
    ca.h = __float2bfloat16(a);
    cb.h = __float2bfloat16(b);
    return (unsigned int)ca.u | ((unsigned int)cb.u << 16);
}

// -------- CSR bucketing: per-graph histogram + prefix scan + eid scatter -----------
// One block per graph. Buckets let the aggregation be a register-accumulated GATHER
// (no LDS/global atomics in the hot kernel — R3 showed DS atomics saturate the CU).
__global__ __launch_bounds__(512) void build_buckets(
    const int* __restrict__ dst, int* __restrict__ bucket,
    int* __restrict__ start, int* __restrict__ deg)
{
    __shared__ int cnt[512];
    __shared__ int pre[512];
    __shared__ int pre2[512];
    const int g = blockIdx.x;
    const int t = threadIdx.x;
    const int eb = g * EPG;
    cnt[t] = 0;
    __syncthreads();
    #pragma unroll
    for (int i = 0; i < EPG / 512; ++i)
        atomicAdd(&cnt[dst[eb + i * 512 + t] - g * SS], 1);
    __syncthreads();
    int v = cnt[t];
    int* a = pre; int* b = pre2;
    a[t] = v;
    __syncthreads();
    for (int off = 1; off < 512; off <<= 1) {   // Hillis-Steele inclusive scan
        int s = a[t] + ((t >= off) ? a[t - off] : 0);
        b[t] = s;
        __syncthreads();
        int* tmp = a; a = b; b = tmp;
    }
    int ex = a[t] - v;                          // exclusive prefix (graph-local)
    start[g * SS + t] = ex;
    deg[g * SS + t]   = v;
    cnt[t] = ex;                                // reuse as cursor
    __syncthreads();
    #pragma unroll
    for (int i = 0; i < EPG / 512; ++i) {
        int e = eb + i * 512 + t;
        int d = dst[e] - g * SS;
        int p = atomicAdd(&cnt[d], 1);
        bucket[eb + p] = e;
    }
}

// -------- GINE aggregation as gather: z[n] = x[n] + sum_in relu(x[src]+ea[e]) ------
// 32 lanes per node (float4 each -> 512B coalesced rows), 8 nodes/block.
// Block swizzle w=(L&7)*256+(L>>3) pins graphs 4x..4x+3 to XCD x (x rows L2-hit).
__global__ __launch_bounds__(256) void gine_gather(
    const float* __restrict__ x, const int* __restrict__ src,
    const float* __restrict__ ea, const int* __restrict__ bucket,
    const int* __restrict__ start, const int* __restrict__ deg,
    float* __restrict__ z)
{
    const int L = blockIdx.x;
    const int w = (L & 7) * 256 + (L >> 3);
    const int grp = threadIdx.x >> 5;
    const int l   = threadIdx.x & 31;
    const int n   = w * 8 + grp;
    const int g   = n >> 9;
    const int st  = g * EPG + start[n];
    const int de  = deg[n];

    float4 acc = *(const float4*)(x + (size_t)n * DD + l * 4);  // z = x + agg
    int eid0 = (de > 0) ? bucket[st] : 0;
    int s0   = (de > 0) ? src[eid0] : 0;
    for (int i = 0; i < de; ++i) {
        int eid1 = (i + 1 < de) ? bucket[st + i + 1] : 0;   // 1-ahead pipeline on the
        int s1   = (i + 1 < de) ? src[eid1] : 0;            // pointer chain
        float4 ev = *(const float4*)(ea + (size_t)eid0 * DD + l * 4);
        float4 xv = *(const float4*)(x  + (size_t)s0   * DD + l * 4);
        acc.x += fmaxf(xv.x + ev.x, 0.f);
        acc.y += fmaxf(xv.y + ev.y, 0.f);
        acc.z += fmaxf(xv.z + ev.z, 0.f);
        acc.w += fmaxf(xv.w + ev.w, 0.f);
        eid0 = eid1; s0 = s1;
    }
    *(float4*)(z + (size_t)n * DD + l * 4) = acc;
}

// ---------------- bf16 MFMA GEMM, BT layout: out = epi(A @ W^T + bias) (+res) ------
// A: [M,K] f32 row-major, W: [Ncols,K] f32 row-major. BM=BN=128, BK=64, 4 waves.
// STATS: fuse per-column sum/sumsq (BatchNorm) — requires Ncols==128, gridDim.y==1.
template<bool RELU, bool HAS_RES, bool STATS>
__global__ __launch_bounds__(256) void gemm_bt(
    const float* __restrict__ A,
    const float* __restrict__ W, const float* __restrict__ bias,
    const float* __restrict__ res, float* __restrict__ out,
    float* __restrict__ stats, int K, int Ncols)
{
    constexpr int BK = 64;
    __shared__ unsigned short Ash[128 * BK];
    __shared__ unsigned short Wsh[128 * BK];
    __shared__ float ssh[256];
    const int tid  = threadIdx.x;
    const int lane = tid & 63;
    const int wid  = tid >> 6;
    const int wm   = wid >> 1, wn = wid & 1;
    const int brow = blockIdx.x * 128;
    const int bcol = blockIdx.y * 128;

    f32x4 acc[4][4] = {};

    for (int k0 = 0; k0 < K; k0 += BK) {
        #pragma unroll
        for (int i = 0; i < 4; ++i) {
            int idx = tid + 256 * i;
            int row = idx >> 3;
            int kc  = (idx & 7) * 8;
            int off = row * (BK * 2) + ((kc * 2) ^ ((row & 7) << 4));
            {
                size_t base = (size_t)(brow + row) * K + k0 + kc;
                float4 lo = *(const float4*)(A + base);
                float4 hi = *(const float4*)(A + base + 4);
                int4 pw = { (int)pk2(lo.x, lo.y), (int)pk2(lo.z, lo.w),
                            (int)pk2(hi.x, hi.y), (int)pk2(hi.z, hi.w) };
                *(int4*)((char*)Ash + off) = pw;
            }
            {
                const float* sp = W + (size_t)(bcol + row) * K + k0 + kc;
                float4 lo = *(const float4*)sp;
                float4 hi = *(const float4*)(sp + 4);
                int4 pw = { (int)pk2(lo.x, lo.y), (int)pk2(lo.z, lo.w),
                            (int)pk2(hi.x, hi.y), (int)pk2(hi.z, hi.w) };
                *(int4*)((char*)Wsh + off) = pw;
            }
        }
        __syncthreads();
        #pragma unroll
        for (int ks = 0; ks < BK / 32; ++ks) {
            short8 af[4], bf[4];
            const int kf = ks * 32 + (lane >> 4) * 8;
            #pragma unroll
            for (int mt = 0; mt < 4; ++mt) {
                int row = wm * 64 + mt * 16 + (lane & 15);
                int off = row * (BK * 2) + ((kf * 2) ^ ((row & 7) << 4));
                af[mt] = *(const short8*)((const char*)Ash + off);
            }
            #pragma unroll
            for (int nt = 0; nt < 4; ++nt) {
                int row = wn * 64 + nt * 16 + (lane & 15);
                int off = row * (BK * 2) + ((kf * 2) ^ ((row & 7) << 4));
                bf[nt] = *(const short8*)((const char*)Wsh + off);
            }
            #pragma unroll
            for (int mt = 0; mt < 4; ++mt)
                #pragma unroll
                for (int nt = 0; nt < 4; ++nt)
                    acc[mt][nt] = __builtin_amdgcn_mfma_f32_16x16x32_bf16(
                        af[mt], bf[nt], acc[mt][nt], 0, 0, 0);
        }
        __syncthreads();
    }

    if (STATS) { ssh[tid] = 0.f; __syncthreads(); }

    float cs[4] = {}, cs2[4] = {};
    // epilogue: C/D layout col=lane&15, row=(lane>>4)*4+j (verified gfx950 mapping)
    #pragma unroll
    for (int mt = 0; mt < 4; ++mt) {
        #pragma unroll
        for (int nt = 0; nt < 4; ++nt) {
            int col = bcol + wn * 64 + nt * 16 + (lane & 15);
            float bv = bias[col];
            #pragma unroll
            for (int j = 0; j < 4; ++j) {
                int row = brow + wm * 64 + mt * 16 + (lane >> 4) * 4 + j;
                float v = acc[mt][nt][j] + bv;
                if (RELU) v = fmaxf(v, 0.f);
                if (HAS_RES) v += res[(size_t)row * Ncols + col];
                out[(size_t)row * Ncols + col] = v;
                if (STATS) { cs[nt] += v; cs2[nt] += v * v; }
            }
        }
    }
    if (STATS) {
        #pragma unroll
        for (int nt = 0; nt < 4; ++nt) {
            float s = cs[nt], s2 = cs2[nt];
            s  += __shfl_xor(s, 16);  s  += __shfl_xor(s, 32);
            s2 += __shfl_xor(s2, 16); s2 += __shfl_xor(s2, 32);
            if ((lane >> 4) == 0) {
                int cl = wn * 64 + nt * 16 + (lane & 15);
                atomicAdd(&ssh[cl], s);
                atomicAdd(&ssh[128 + cl], s2);
            }
        }
        __syncthreads();
        if (tid < 128) {
            atomicAdd(&stats[tid], ssh[tid]);
            atomicAdd(&stats[DD + tid], ssh[128 + tid]);
        }
    }
}

// ---------------- per-(graph,head) attention, f32, K/V staged in LDS ----------------
__global__ __launch_bounds__(512) void attn_kernel(
    const float* __restrict__ qkv, float* __restrict__ o)
{
    int g = blockIdx.x >> 3;
    int h = blockIdx.x & 7;
    __shared__ float Ksh[SS][DHD];
    __shared__ float Vsh[SS][DHD];
    int t = threadIdx.x;
    const float* rowp = qkv + (size_t)(g * SS + t) * 384;
    {
        const float* kb = rowp + 128 + h * DHD;
        const float* vb = rowp + 256 + h * DHD;
        #pragma unroll
        for (int i = 0; i < 4; ++i) {
            ((float4*)Ksh[t])[i] = ((const float4*)kb)[i];
            ((float4*)Vsh[t])[i] = ((const float4*)vb)[i];
        }
    }
    float q[DHD];
    {
        const float* qb = rowp + h * DHD;
        #pragma unroll
        for (int i = 0; i < 4; ++i) ((float4*)q)[i] = ((const float4*)qb)[i];
    }
    __syncthreads();
    float acc[DHD] = {};
    float l = 0.f;
    for (int j = 0; j < SS; ++j) {
        float s = 0.f;
        #pragma unroll
        for (int d = 0; d < DHD; ++d) s += q[d] * Ksh[j][d];
        float e = __expf(s * 0.25f);   // logits are O(1): max-subtraction unnecessary
        l += e;
        #pragma unroll
        for (int d = 0; d < DHD; ++d) acc[d] += e * Vsh[j][d];
    }
    float inv = 1.f / l;
    float* ob = o + (size_t)(g * SS + t) * DD + h * DHD;
    #pragma unroll
    for (int d = 0; d < DHD; ++d) acc[d] *= inv;
    #pragma unroll
    for (int i = 0; i < 4; ++i) ((float4*)ob)[i] = ((const float4*)acc)[i];
}

// ---------------- h = BN(t_local) + BN(t_attn) ----------------
__global__ __launch_bounds__(256) void combine_kernel(
    const float* __restrict__ tl, const float* __restrict__ ta,
    const float* __restrict__ stl, const float* __restrict__ sta,
    const float* __restrict__ g1, const float* __restrict__ b1,
    const float* __restrict__ g2, const float* __restrict__ b2,
    float* __restrict__ out)
{
    int idx = blockIdx.x * 256 + threadIdx.x;
    int c0 = (idx * 4) & (DD - 1);
    float4 vl = ((const float4*)tl)[idx];
    float4 va = ((const float4*)ta)[idx];
    float r[4];
    const float* pl = (const float*)&vl;
    const float* pa = (const float*)&va;
    #pragma unroll
    for (int k = 0; k < 4; ++k) {
        int c = c0 + k;
        float mu1 = stl[c] * (1.f / NN);
        float v1  = stl[DD + c] * (1.f / NN) - mu1 * mu1;
        float rs1 = rsqrtf(v1 + BN_EPS);
        float mu2 = sta[c] * (1.f / NN);
        float v2  = sta[DD + c] * (1.f / NN) - mu2 * mu2;
        float rs2 = rsqrtf(v2 + BN_EPS);
        r[k] = (pl[k] - mu1) * rs1 * g1[c] + b1[c]
             + (pa[k] - mu2) * rs2 * g2[c] + b2[c];
    }
    ((float4*)out)[idx] = *(float4*)r;
}

// ---------------- out = BN(t2) ----------------
__global__ __launch_bounds__(256) void final_bn(
    const float* __restrict__ t2, const float* __restrict__ st,
    const float* __restrict__ g, const float* __restrict__ b,
    float* __restrict__ out)
{
    int idx = blockIdx.x * 256 + threadIdx.x;
    int c0 = (idx * 4) & (DD - 1);
    float4 v = ((const float4*)t2)[idx];
    const float* pv = (const float*)&v;
    float r[4];
    #pragma unroll
    for (int k = 0; k < 4; ++k) {
        int c = c0 + k;
        float mu = st[c] * (1.f / NN);
        float va = st[DD + c] * (1.f / NN) - mu * mu;
        float rs = rsqrtf(va + BN_EPS);
        r[k] = (pv[k] - mu) * rs * g[c] + b[c];
    }
    ((float4*)out)[idx] = *(float4*)r;
}

extern "C" void kernel_launch(void* const* d_in, const int* in_sizes, int n_in,
                              void* d_out, int out_size, void* d_ws, size_t ws_size,
                              hipStream_t stream) {
    const float* x    = (const float*)d_in[0];
    const int*   ei   = (const int*)d_in[1];
    const float* ea   = (const float*)d_in[2];
    const float* gw1  = (const float*)d_in[3];
    const float* gb1  = (const float*)d_in[4];
    const float* gw2  = (const float*)d_in[5];
    const float* gb2  = (const float*)d_in[6];
    const float* bn1lg= (const float*)d_in[7];
    const float* bn1lb= (const float*)d_in[8];
    const float* aiw  = (const float*)d_in[9];
    const float* aib  = (const float*)d_in[10];
    const float* aow  = (const float*)d_in[11];
    const float* aob  = (const float*)d_in[12];
    const float* bn1ag= (const float*)d_in[13];
    const float* bn1ab= (const float*)d_in[14];
    const float* fw1  = (const float*)d_in[15];
    const float* fb1  = (const float*)d_in[16];
    const float* fw2  = (const float*)d_in[17];
    const float* fb2  = (const float*)d_in[18];
    const float* bn2g = (const float*)d_in[19];
    const float* bn2b = (const float*)d_in[20];
    float* out = (float*)d_out;
    float* ws  = (float*)d_ws;

    // ws regions (floats). 2,097,152 floats = one [NN,128] matrix.
    float* regA  = ws;                   // z -> qkv(3x) -> f1(2x)   [8 slots]
    float* regB  = ws + 8 * 2097152;     // bucket/start/deg -> h1 -> o_buf [2 slots]
    float* regC  = ws + 10 * 2097152;    // t_local -> t2
    float* regD  = ws + 12 * 2097152;    // t_attn
    float* regE  = ws + 14 * 2097152;    // hbuf
    float* stats = ws + 16 * 2097152;    // 768 floats
    float* z     = regA;
    float* qkv   = regA;
    float* f1    = regA;
    int*   bucket= (int*)regB;           // NE ints; dead before h1 is written
    int*   bstart= (int*)regB + NE;      // NN ints
    int*   bdeg  = (int*)regB + NE + NN; // NN ints
    float* h1    = regB;
    float* o_buf = regB;
    float* t_local = regC;
    float* t2    = regC;
    float* t_attn = regD;
    float* hbuf  = regE;

    hipMemsetAsync(stats, 0, 768 * sizeof(float), stream);

    // --- local branch: bucket edges by dst, then register-accumulated gather
    build_buckets<<<NG, 512, 0, stream>>>(ei + NE, bucket, bstart, bdeg);
    gine_gather<<<NN / 8, 256, 0, stream>>>(x, ei, ea, bucket, bstart, bdeg, z);
    gemm_bt<true, false, false><<<dim3(NN / 128, 1), 256, 0, stream>>>(
        z, gw1, gb1, nullptr, h1, nullptr, 128, 128);
    gemm_bt<false, true, true><<<dim3(NN / 128, 1), 256, 0, stream>>>(
        h1, gw2, gb2, x, t_local, stats, 128, 128);

    // --- global branch (qkv overlays z, which dies after gemm1)
    gemm_bt<false, false, false><<<dim3(NN / 128, 3), 256, 0, stream>>>(
        x, aiw, aib, nullptr, qkv, nullptr, 128, 384);
    attn_kernel<<<NG * NH, 512, 0, stream>>>(qkv, o_buf);
    gemm_bt<false, true, true><<<dim3(NN / 128, 1), 256, 0, stream>>>(
        o_buf, aow, aob, x, t_attn, stats + 256, 128, 128);

    // --- combine + FF
    combine_kernel<<<NN * DD / 4 / 256, 256, 0, stream>>>(
        t_local, t_attn, stats, stats + 256, bn1lg, bn1lb, bn1ag, bn1ab, hbuf);
    gemm_bt<true, false, false><<<dim3(NN / 128, 2), 256, 0, stream>>>(
        hbuf, fw1, fb1, nullptr, f1, nullptr, 128, 256);
    gemm_bt<false, true, true><<<dim3(NN / 128, 1), 256, 0, stream>>>(
        f1, fw2, fb2, hbuf, t2, stats + 512, 256, 128);
    final_bn<<<NN * DD / 4 / 256, 256, 0, stream>>>(t2, stats + 512, bn2g, bn2b, out);
}

// Round 6
// 382.555 us; speedup vs baseline: 1.4224x; 1.1654x over previous
//
#include <hip/hip_runtime.h>
#include <hip/hip_bf16.h>

typedef __attribute__((ext_vector_type(8))) short short8;
typedef __attribute__((ext_vector_type(4))) float f32x4;
typedef __attribute__((ext_vector_type(16))) float f32x16;

#define NN 16384
#define DD 128
#define NE 262144
#define NG 32
#define SS 512
#define NH 8
#define DHD 16
#define EPG 8192   // edges per graph
#define BN_EPS 1e-5f

__device__ __forceinline__ unsigned int pk2(float a, float b) {
    union { __hip_bfloat16 h; unsigned short u; } ca, cb;
    ca.h = __float2bfloat16(a);
    cb.h = __float2bfloat16(b);
    return (unsigned int)ca.u | ((unsigned int)cb.u << 16);
}

__device__ __forceinline__ unsigned short bf16u(float f) {
    union { __hip_bfloat16 h; unsigned short u; } c;
    c.h = __float2bfloat16(f);
    return c.u;
}

// -------- CSR bucketing: per-graph histogram + prefix scan + eid scatter -----------
__global__ __launch_bounds__(512) void build_buckets(
    const int* __restrict__ dst, int* __restrict__ bucket,
    int* __restrict__ start, int* __restrict__ deg)
{
    __shared__ int cnt[512];
    __shared__ int pre[512];
    __shared__ int pre2[512];
    const int g = blockIdx.x;
    const int t = threadIdx.x;
    const int eb = g * EPG;
    cnt[t] = 0;
    __syncthreads();
    #pragma unroll
    for (int i = 0; i < EPG / 512; ++i)
        atomicAdd(&cnt[dst[eb + i * 512 + t] - g * SS], 1);
    __syncthreads();
    int v = cnt[t];
    int* a = pre; int* b = pre2;
    a[t] = v;
    __syncthreads();
    for (int off = 1; off < 512; off <<= 1) {   // Hillis-Steele inclusive scan
        int s = a[t] + ((t >= off) ? a[t - off] : 0);
        b[t] = s;
        __syncthreads();
        int* tmp = a; a = b; b = tmp;
    }
    int ex = a[t] - v;                          // exclusive prefix (graph-local)
    start[g * SS + t] = ex;
    deg[g * SS + t]   = v;
    cnt[t] = ex;                                // reuse as cursor
    __syncthreads();
    #pragma unroll
    for (int i = 0; i < EPG / 512; ++i) {
        int e = eb + i * 512 + t;
        int d = dst[e] - g * SS;
        int p = atomicAdd(&cnt[d], 1);
        bucket[eb + p] = e;
    }
}

// -------- GINE aggregation as gather: z[n] = x[n] + sum_in relu(x[src]+ea[e]) ------
__global__ __launch_bounds__(256) void gine_gather(
    const float* __restrict__ x, const int* __restrict__ src,
    const float* __restrict__ ea, const int* __restrict__ bucket,
    const int* __restrict__ start, const int* __restrict__ deg,
    float* __restrict__ z)
{
    const int L = blockIdx.x;
    const int w = (L & 7) * 256 + (L >> 3);
    const int grp = threadIdx.x >> 5;
    const int l   = threadIdx.x & 31;
    const int n   = w * 8 + grp;
    const int g   = n >> 9;
    const int st  = g * EPG + start[n];
    const int de  = deg[n];

    float4 acc = *(const float4*)(x + (size_t)n * DD + l * 4);  // z = x + agg
    int eid0 = (de > 0) ? bucket[st] : 0;
    int s0   = (de > 0) ? src[eid0] : 0;
    for (int i = 0; i < de; ++i) {
        int eid1 = (i + 1 < de) ? bucket[st + i + 1] : 0;   // 1-ahead pipeline
        int s1   = (i + 1 < de) ? src[eid1] : 0;
        float4 ev = *(const float4*)(ea + (size_t)eid0 * DD + l * 4);
        float4 xv = *(const float4*)(x  + (size_t)s0   * DD + l * 4);
        acc.x += fmaxf(xv.x + ev.x, 0.f);
        acc.y += fmaxf(xv.y + ev.y, 0.f);
        acc.z += fmaxf(xv.z + ev.z, 0.f);
        acc.w += fmaxf(xv.w + ev.w, 0.f);
        eid0 = eid1; s0 = s1;
    }
    *(float4*)(z + (size_t)n * DD + l * 4) = acc;
}

// ---------------- bf16 MFMA GEMM, BT layout: out = epi(A @ W^T + bias) (+res) ------
template<bool RELU, bool HAS_RES, bool STATS>
__global__ __launch_bounds__(256) void gemm_bt(
    const float* __restrict__ A,
    const float* __restrict__ W, const float* __restrict__ bias,
    const float* __restrict__ res, float* __restrict__ out,
    float* __restrict__ stats, int K, int Ncols)
{
    constexpr int BK = 64;
    __shared__ unsigned short Ash[128 * BK];
    __shared__ unsigned short Wsh[128 * BK];
    __shared__ float ssh[256];
    const int tid  = threadIdx.x;
    const int lane = tid & 63;
    const int wid  = tid >> 6;
    const int wm   = wid >> 1, wn = wid & 1;
    const int brow = blockIdx.x * 128;
    const int bcol = blockIdx.y * 128;

    f32x4 acc[4][4] = {};

    for (int k0 = 0; k0 < K; k0 += BK) {
        #pragma unroll
        for (int i = 0; i < 4; ++i) {
            int idx = tid + 256 * i;
            int row = idx >> 3;
            int kc  = (idx & 7) * 8;
            int off = row * (BK * 2) + ((kc * 2) ^ ((row & 7) << 4));
            {
                size_t base = (size_t)(brow + row) * K + k0 + kc;
                float4 lo = *(const float4*)(A + base);
                float4 hi = *(const float4*)(A + base + 4);
                int4 pw = { (int)pk2(lo.x, lo.y), (int)pk2(lo.z, lo.w),
                            (int)pk2(hi.x, hi.y), (int)pk2(hi.z, hi.w) };
                *(int4*)((char*)Ash + off) = pw;
            }
            {
                const float* sp = W + (size_t)(bcol + row) * K + k0 + kc;
                float4 lo = *(const float4*)sp;
                float4 hi = *(const float4*)(sp + 4);
                int4 pw = { (int)pk2(lo.x, lo.y), (int)pk2(lo.z, lo.w),
                            (int)pk2(hi.x, hi.y), (int)pk2(hi.z, hi.w) };
                *(int4*)((char*)Wsh + off) = pw;
            }
        }
        __syncthreads();
        #pragma unroll
        for (int ks = 0; ks < BK / 32; ++ks) {
            short8 af[4], bf[4];
            const int kf = ks * 32 + (lane >> 4) * 8;
            #pragma unroll
            for (int mt = 0; mt < 4; ++mt) {
                int row = wm * 64 + mt * 16 + (lane & 15);
                int off = row * (BK * 2) + ((kf * 2) ^ ((row & 7) << 4));
                af[mt] = *(const short8*)((const char*)Ash + off);
            }
            #pragma unroll
            for (int nt = 0; nt < 4; ++nt) {
                int row = wn * 64 + nt * 16 + (lane & 15);
                int off = row * (BK * 2) + ((kf * 2) ^ ((row & 7) << 4));
                bf[nt] = *(const short8*)((const char*)Wsh + off);
            }
            #pragma unroll
            for (int mt = 0; mt < 4; ++mt)
                #pragma unroll
                for (int nt = 0; nt < 4; ++nt)
                    acc[mt][nt] = __builtin_amdgcn_mfma_f32_16x16x32_bf16(
                        af[mt], bf[nt], acc[mt][nt], 0, 0, 0);
        }
        __syncthreads();
    }

    if (STATS) { ssh[tid] = 0.f; __syncthreads(); }

    float cs[4] = {}, cs2[4] = {};
    #pragma unroll
    for (int mt = 0; mt < 4; ++mt) {
        #pragma unroll
        for (int nt = 0; nt < 4; ++nt) {
            int col = bcol + wn * 64 + nt * 16 + (lane & 15);
            float bv = bias[col];
            #pragma unroll
            for (int j = 0; j < 4; ++j) {
                int row = brow + wm * 64 + mt * 16 + (lane >> 4) * 4 + j;
                float v = acc[mt][nt][j] + bv;
                if (RELU) v = fmaxf(v, 0.f);
                if (HAS_RES) v += res[(size_t)row * Ncols + col];
                out[(size_t)row * Ncols + col] = v;
                if (STATS) { cs[nt] += v; cs2[nt] += v * v; }
            }
        }
    }
    if (STATS) {
        #pragma unroll
        for (int nt = 0; nt < 4; ++nt) {
            float s = cs[nt], s2 = cs2[nt];
            s  += __shfl_xor(s, 16);  s  += __shfl_xor(s, 32);
            s2 += __shfl_xor(s2, 16); s2 += __shfl_xor(s2, 32);
            if ((lane >> 4) == 0) {
                int cl = wn * 64 + nt * 16 + (lane & 15);
                atomicAdd(&ssh[cl], s);
                atomicAdd(&ssh[128 + cl], s2);
            }
        }
        __syncthreads();
        if (tid < 128) {
            atomicAdd(&stats[tid], ssh[tid]);
            atomicAdd(&stats[DD + tid], ssh[128 + tid]);
        }
    }
}

// ---------------- MFMA flash attention: block = (graph, head, 128-query chunk) -----
// Swapped QK^T (S^T = K @ Q^T via one 32x32x16 mfma, K-dim = DH = 16) makes the
// P-row lane-local: per-lane exp/lsum, then pk2 + v_permlane32_swap_b32 assembles
// PV's A-fragments in place (m214-verified pairing). O accumulated by 2 PV mfmas
// per 32-key block (B = V^T rows; cols 16..31 of D are dead, DH=16).
__global__ __launch_bounds__(256) void attn_mfma(
    const float* __restrict__ qkv, float* __restrict__ o)
{
    __shared__ unsigned short Ksh[SS * 20];   // K rows padded to 20 shorts (40 B)
    __shared__ unsigned short VT[16 * 520];   // V^T rows padded to 520 shorts
    const int id = blockIdx.x;
    const int g  = ((id >> 3) & 3) * 8 + (id & 7);  // id%8 == g%8 -> XCD-pinned slab
    const int h  = (id >> 5) & 7;
    const int qc = id >> 8;
    const int t  = threadIdx.x;
    const int wid = t >> 6;
    const int l   = t & 63;
    const int lq  = l & 31;
    const int hi  = l >> 5;

    // ---- stage K (row-major bf16) and V^T (bf16) for this (g,h) ----
    #pragma unroll
    for (int iter = 0; iter < 2; ++iter) {
        int key = iter * 256 + t;
        const float* kp = qkv + (size_t)(g * SS + key) * 384 + 128 + h * DHD;
        unsigned short us[16];
        #pragma unroll
        for (int i = 0; i < 4; ++i) {
            float4 v = *(const float4*)(kp + i * 4);
            us[i*4+0] = bf16u(v.x); us[i*4+1] = bf16u(v.y);
            us[i*4+2] = bf16u(v.z); us[i*4+3] = bf16u(v.w);
        }
        unsigned short* kr = Ksh + key * 20;
        #pragma unroll
        for (int i = 0; i < 4; ++i) *(uint2*)(kr + i * 4) = *(const uint2*)(us + i * 4);
        const float* vp = kp + 128;
        #pragma unroll
        for (int i = 0; i < 4; ++i) {
            float4 v = *(const float4*)(vp + i * 4);
            VT[(i*4+0) * 520 + key] = bf16u(v.x);
            VT[(i*4+1) * 520 + key] = bf16u(v.y);
            VT[(i*4+2) * 520 + key] = bf16u(v.z);
            VT[(i*4+3) * 520 + key] = bf16u(v.w);
        }
    }

    // ---- per-wave Q fragment (B operand of QK mfma): 32 queries x 16 dh ----
    const int q0 = qc * 128 + wid * 32;
    short8 qf;
    {
        const float* qp = qkv + (size_t)(g * SS + q0 + lq) * 384 + h * DHD + hi * 8;
        float4 a = *(const float4*)qp;
        float4 b = *(const float4*)(qp + 4);
        union { unsigned int u[4]; short8 s; } pu;
        pu.u[0] = pk2(a.x, a.y); pu.u[1] = pk2(a.z, a.w);
        pu.u[2] = pk2(b.x, b.y); pu.u[3] = pk2(b.z, b.w);
        qf = pu.s;
    }
    __syncthreads();

    f32x16 acc = {};
    const f32x16 zero = {};
    float lsum = 0.f;
    for (int kb = 0; kb < 16; ++kb) {
        short8 kf;   // A-frag: K[key = kb*32 + lq][dh = hi*8 + i]
        {
            const unsigned short* kr = Ksh + (kb * 32 + lq) * 20 + hi * 8;
            union { uint2 u[2]; short8 s; } ku;
            ku.u[0] = *(const uint2*)kr;
            ku.u[1] = *(const uint2*)(kr + 4);
            kf = ku.s;
        }
        f32x16 st = __builtin_amdgcn_mfma_f32_32x32x16_bf16(kf, qf, zero, 0, 0, 0);
        float p[16];
        #pragma unroll
        for (int j = 0; j < 16; ++j) {
            p[j] = __expf(st[j] * 0.25f);   // logits O(1); no max-subtraction needed
            lsum += p[j];
        }
        // pack P to bf16; permlane32_swap pairs (w_i, w_{i+2}) -> PV A-fragments
        unsigned int w0 = pk2(p[0],  p[1]),  w1 = pk2(p[2],  p[3]);
        unsigned int w2 = pk2(p[4],  p[5]),  w3 = pk2(p[6],  p[7]);
        unsigned int w4 = pk2(p[8],  p[9]),  w5 = pk2(p[10], p[11]);
        unsigned int w6 = pk2(p[12], p[13]), w7 = pk2(p[14], p[15]);
        asm("v_permlane32_swap_b32 %0, %1" : "+v"(w0), "+v"(w2));
        asm("v_permlane32_swap_b32 %0, %1" : "+v"(w1), "+v"(w3));
        asm("v_permlane32_swap_b32 %0, %1" : "+v"(w4), "+v"(w6));
        asm("v_permlane32_swap_b32 %0, %1" : "+v"(w5), "+v"(w7));
        union { unsigned int u[4]; short8 s; } pa0, pa1;
        pa0.u[0] = w0; pa0.u[1] = w1; pa0.u[2] = w2; pa0.u[3] = w3;
        pa1.u[0] = w4; pa1.u[1] = w5; pa1.u[2] = w6; pa1.u[3] = w7;
        // B-frags: V^T[d = lq&15][keys kb*32 + chunk*16 + hi*8 + i]
        const unsigned short* vr = VT + (lq & 15) * 520 + kb * 32 + hi * 8;
        short8 vf0 = *(const short8*)vr;
        short8 vf1 = *(const short8*)(vr + 16);
        acc = __builtin_amdgcn_mfma_f32_32x32x16_bf16(pa0.s, vf0, acc, 0, 0, 0);
        acc = __builtin_amdgcn_mfma_f32_32x32x16_bf16(pa1.s, vf1, acc, 0, 0, 0);
    }

    // ---- normalize (lsum split across lane pairs) and write O ----
    lsum += __shfl_xor(lsum, 32);
    float rinv = 1.f / lsum;
    float ov[16];
    #pragma unroll
    for (int j = 0; j < 16; ++j) {
        int row = (j & 3) + 8 * (j >> 2) + 4 * hi;   // C/D row mapping (32x32)
        ov[j] = acc[j] * __shfl(rinv, row);          // all lanes execute the shfl
    }
    if (lq < DHD) {
        #pragma unroll
        for (int j = 0; j < 16; ++j) {
            int row = (j & 3) + 8 * (j >> 2) + 4 * hi;
            o[(size_t)(g * SS + q0 + row) * DD + h * DHD + lq] = ov[j];
        }
    }
}

// ---------------- h = BN(t_local) + BN(t_attn) ----------------
__global__ __launch_bounds__(256) void combine_kernel(
    const float* __restrict__ tl, const float* __restrict__ ta,
    const float* __restrict__ stl, const float* __restrict__ sta,
    const float* __restrict__ g1, const float* __restrict__ b1,
    const float* __restrict__ g2, const float* __restrict__ b2,
    float* __restrict__ out)
{
    int idx = blockIdx.x * 256 + threadIdx.x;
    int c0 = (idx * 4) & (DD - 1);
    float4 vl = ((const float4*)tl)[idx];
    float4 va = ((const float4*)ta)[idx];
    float r[4];
    const float* pl = (const float*)&vl;
    const float* pa = (const float*)&va;
    #pragma unroll
    for (int k = 0; k < 4; ++k) {
        int c = c0 + k;
        float mu1 = stl[c] * (1.f / NN);
        float v1  = stl[DD + c] * (1.f / NN) - mu1 * mu1;
        float rs1 = rsqrtf(v1 + BN_EPS);
        float mu2 = sta[c] * (1.f / NN);
        float v2  = sta[DD + c] * (1.f / NN) - mu2 * mu2;
        float rs2 = rsqrtf(v2 + BN_EPS);
        r[k] = (pl[k] - mu1) * rs1 * g1[c] + b1[c]
             + (pa[k] - mu2) * rs2 * g2[c] + b2[c];
    }
    ((float4*)out)[idx] = *(float4*)r;
}

// ---------------- out = BN(t2) ----------------
__global__ __launch_bounds__(256) void final_bn(
    const float* __restrict__ t2, const float* __restrict__ st,
    const float* __restrict__ g, const float* __restrict__ b,
    float* __restrict__ out)
{
    int idx = blockIdx.x * 256 + threadIdx.x;
    int c0 = (idx * 4) & (DD - 1);
    float4 v = ((const float4*)t2)[idx];
    const float* pv = (const float*)&v;
    float r[4];
    #pragma unroll
    for (int k = 0; k < 4; ++k) {
        int c = c0 + k;
        float mu = st[c] * (1.f / NN);
        float va = st[DD + c] * (1.f / NN) - mu * mu;
        float rs = rsqrtf(va + BN_EPS);
        r[k] = (pv[k] - mu) * rs * g[c] + b[c];
    }
    ((float4*)out)[idx] = *(float4*)r;
}

extern "C" void kernel_launch(void* const* d_in, const int* in_sizes, int n_in,
                              void* d_out, int out_size, void* d_ws, size_t ws_size,
                              hipStream_t stream) {
    const float* x    = (const float*)d_in[0];
    const int*   ei   = (const int*)d_in[1];
    const float* ea   = (const float*)d_in[2];
    const float* gw1  = (const float*)d_in[3];
    const float* gb1  = (const float*)d_in[4];
    const float* gw2  = (const float*)d_in[5];
    const float* gb2  = (const float*)d_in[6];
    const float* bn1lg= (const float*)d_in[7];
    const float* bn1lb= (const float*)d_in[8];
    const float* aiw  = (const float*)d_in[9];
    const float* aib  = (const float*)d_in[10];
    const float* aow  = (const float*)d_in[11];
    const float* aob  = (const float*)d_in[12];
    const float* bn1ag= (const float*)d_in[13];
    const float* bn1ab= (const float*)d_in[14];
    const float* fw1  = (const float*)d_in[15];
    const float* fb1  = (const float*)d_in[16];
    const float* fw2  = (const float*)d_in[17];
    const float* fb2  = (const float*)d_in[18];
    const float* bn2g = (const float*)d_in[19];
    const float* bn2b = (const float*)d_in[20];
    float* out = (float*)d_out;
    float* ws  = (float*)d_ws;

    // ws regions (floats). 2,097,152 floats = one [NN,128] matrix.
    float* regA  = ws;                   // z -> qkv(3x) -> f1(2x)   [8 slots]
    float* regB  = ws + 8 * 2097152;     // bucket/start/deg -> h1 -> o_buf [2 slots]
    float* regC  = ws + 10 * 2097152;    // t_local -> t2
    float* regD  = ws + 12 * 2097152;    // t_attn
    float* regE  = ws + 14 * 2097152;    // hbuf
    float* stats = ws + 16 * 2097152;    // 768 floats
    float* z     = regA;
    float* qkv   = regA;
    float* f1    = regA;
    int*   bucket= (int*)regB;           // NE ints; dead before h1 is written
    int*   bstart= (int*)regB + NE;      // NN ints
    int*   bdeg  = (int*)regB + NE + NN; // NN ints
    float* h1    = regB;
    float* o_buf = regB;
    float* t_local = regC;
    float* t2    = regC;
    float* t_attn = regD;
    float* hbuf  = regE;

    hipMemsetAsync(stats, 0, 768 * sizeof(float), stream);

    // --- local branch: bucket edges by dst, then register-accumulated gather
    build_buckets<<<NG, 512, 0, stream>>>(ei + NE, bucket, bstart, bdeg);
    gine_gather<<<NN / 8, 256, 0, stream>>>(x, ei, ea, bucket, bstart, bdeg, z);
    gemm_bt<true, false, false><<<dim3(NN / 128, 1), 256, 0, stream>>>(
        z, gw1, gb1, nullptr, h1, nullptr, 128, 128);
    gemm_bt<false, true, true><<<dim3(NN / 128, 1), 256, 0, stream>>>(
        h1, gw2, gb2, x, t_local, stats, 128, 128);

    // --- global branch (qkv overlays z, which dies after gemm1)
    gemm_bt<false, false, false><<<dim3(NN / 128, 3), 256, 0, stream>>>(
        x, aiw, aib, nullptr, qkv, nullptr, 128, 384);
    attn_mfma<<<NG * NH * 4, 256, 0, stream>>>(qkv, o_buf);
    gemm_bt<false, true, true><<<dim3(NN / 128, 1), 256, 0, stream>>>(
        o_buf, aow, aob, x, t_attn, stats + 256, 128, 128);

    // --- combine + FF
    combine_kernel<<<NN * DD / 4 / 256, 256, 0, stream>>>(
        t_local, t_attn, stats, stats + 256, bn1lg, bn1lb, bn1ag, bn1ab, hbuf);
    gemm_bt<true, false, false><<<dim3(NN / 128, 2), 256, 0, stream>>>(
        hbuf, fw1, fb1, nullptr, f1, nullptr, 128, 256);
    gemm_bt<false, true, true><<<dim3(NN / 128, 1), 256, 0, stream>>>(
        f1, fw2, fb2, hbuf, t2, stats + 512, 256, 128);
    final_bn<<<NN * DD / 4 / 256, 256, 0, stream>>>(t2, stats + 512, bn2g, bn2b, out);
}